// Round 1
// 394.835 us; speedup vs baseline: 1.2078x; 1.2078x over previous
//
#include <hip/hip_runtime.h>

// SoftReordering: B=16, S=1024, E=1024, W=7 (fp32 in/out)
// out[b,t,e] = tanh( sum_w sigmoid(logit[b,t,w]) * win[b,t,w,e] )
// logit[b,t,v] = sum_{w,e} win[b,t,w,e] * weight[t, v, w*E+e] + bias[t,v]
// win[b,t,w,e] = x[b, t+w-3, e]  (0 if out of range)

#define Bq 16
#define Sq 1024
#define Eq 1024
#define Wq 7
#define HWq 3
#define WEq (Wq * Eq)    // 7168
#define WWEq (Wq * WEq)  // 50176

__global__ __launch_bounds__(256, 2) void soft_reorder_kernel(
    const float* __restrict__ x,      // [B,S,E]
    const float* __restrict__ weight, // [S,W,W*E]
    const float* __restrict__ bias,   // [S,W]
    float* __restrict__ out)          // [B,S,E]
{
    const int bid = blockIdx.x;
    // XCD swizzle: block i -> XCD i%8; keep contiguous t ranges on one XCD
    const int t = (bid & 7) * (Sq / 8) + (bid >> 3);
    const int tid = threadIdx.x;
    const int bg = tid >> 6;   // wave id 0..3 -> batch group (4 batches each)
    const int ks = tid & 63;   // e float4-slot within group

    __shared__ float red[4][4][28];   // [bg][quarter][bi*7+v]
    __shared__ float gates[Bq][8];

    const float* wt = weight + (size_t)t * WWEq;

    // ---- Phase 1: logits (register-blocked: 4 batches x 7 v per thread) ----
    float acc[4][7];
#pragma unroll
    for (int bi = 0; bi < 4; ++bi)
#pragma unroll
        for (int v = 0; v < Wq; ++v) acc[bi][v] = 0.f;

#pragma unroll
    for (int i4 = 0; i4 < 4; ++i4) {
        const int e = (ks + i4 * 64) * 4;   // lanes ks consecutive -> 1KB coalesced
#pragma unroll
        for (int w = 0; w < Wq; ++w) {
            const int row = t + w - HWq;
            if ((unsigned)row < (unsigned)Sq) {
                // 7 weight float4 loads, each reused for 4 batches (28 FMA4 each)
                float4 wv[Wq];
#pragma unroll
                for (int v = 0; v < Wq; ++v)
                    wv[v] = *(const float4*)(wt + (size_t)v * WEq + w * Eq + e);
#pragma unroll
                for (int bi = 0; bi < 4; ++bi) {
                    const int b = bg * 4 + bi;
                    const float4 xv = *(const float4*)(x + ((size_t)b * Sq + row) * Eq + e);
#pragma unroll
                    for (int v = 0; v < Wq; ++v) {
                        acc[bi][v] = fmaf(xv.x, wv[v].x, acc[bi][v]);
                        acc[bi][v] = fmaf(xv.y, wv[v].y, acc[bi][v]);
                        acc[bi][v] = fmaf(xv.z, wv[v].z, acc[bi][v]);
                        acc[bi][v] = fmaf(xv.w, wv[v].w, acc[bi][v]);
                    }
                }
            }
        }
    }

    // Reduce over ks lanes: 4-step butterfly within 16-lane groups...
#pragma unroll
    for (int bi = 0; bi < 4; ++bi) {
#pragma unroll
        for (int v = 0; v < Wq; ++v) {
            float s = acc[bi][v];
            s += __shfl_xor(s, 1);
            s += __shfl_xor(s, 2);
            s += __shfl_xor(s, 4);
            s += __shfl_xor(s, 8);
            acc[bi][v] = s;
        }
    }
    // ...then 4 partials per wave land in LDS
    if ((ks & 15) == 0) {
        const int q = ks >> 4;  // 0..3
#pragma unroll
        for (int bi = 0; bi < 4; ++bi)
#pragma unroll
            for (int v = 0; v < Wq; ++v)
                red[bg][q][bi * 7 + v] = acc[bi][v];
    }
    __syncthreads();

    // Final fold: 112 (b,v) pairs, one thread each
    if (tid < 4 * 28) {
        const int g = tid / 28;        // bg
        const int r = tid - g * 28;    // bi*7 + v
        const int bi = r / 7;
        const int v = r - bi * 7;
        const float s = red[g][0][r] + red[g][1][r] + red[g][2][r] + red[g][3][r];
        const float logit = s + bias[t * Wq + v];
        gates[g * 4 + bi][v] = 1.0f / (1.0f + __expf(-logit));
    }
    __syncthreads();

    // ---- Phase 2: gated sum + tanh ----
    // each thread handles one float4 (e = tid*4) for every batch; x rows are L2-hot
    const int e2 = tid * 4;
#pragma unroll 2
    for (int bb = 0; bb < Bq; ++bb) {
        float g[Wq];
#pragma unroll
        for (int w = 0; w < Wq; ++w) g[w] = gates[bb][w];

        float4 a = make_float4(0.f, 0.f, 0.f, 0.f);
#pragma unroll
        for (int w = 0; w < Wq; ++w) {
            const int row = t + w - HWq;
            if ((unsigned)row < (unsigned)Sq) {
                const float4 xv = *(const float4*)(x + ((size_t)bb * Sq + row) * Eq + e2);
                a.x += g[w] * xv.x;
                a.y += g[w] * xv.y;
                a.z += g[w] * xv.z;
                a.w += g[w] * xv.w;
            }
        }
        float4 o;
        o.x = 1.0f - 2.0f / (1.0f + __expf(2.0f * a.x));
        o.y = 1.0f - 2.0f / (1.0f + __expf(2.0f * a.y));
        o.z = 1.0f - 2.0f / (1.0f + __expf(2.0f * a.z));
        o.w = 1.0f - 2.0f / (1.0f + __expf(2.0f * a.w));
        *(float4*)(out + ((size_t)bb * Sq + t) * Eq + e2) = o;
    }
}

extern "C" void kernel_launch(void* const* d_in, const int* in_sizes, int n_in,
                              void* d_out, int out_size, void* d_ws, size_t ws_size,
                              hipStream_t stream) {
    const float* x = (const float*)d_in[0];      // [16,1024,1024]
    const float* weight = (const float*)d_in[1]; // [1024,7,7168]
    const float* bias = (const float*)d_in[2];   // [1024,7]
    float* out = (float*)d_out;                  // [16,1024,1024]

    soft_reorder_kernel<<<Sq, 256, 0, stream>>>(x, weight, bias, out);
}